// Round 1
// baseline (579.415 us; speedup 1.0000x reference)
//
#include <hip/hip_runtime.h>
#include <hip/hip_bf16.h>

#define NB 4
#define NH 16
#define NS 1024
#define ND 64

typedef __bf16 bf16x8 __attribute__((ext_vector_type(8)));
typedef float f32x4 __attribute__((ext_vector_type(4)));
typedef unsigned short u16x8 __attribute__((ext_vector_type(8)));

// Split f32 -> (hi, lo) bf16 pair. hi = rn(x), lo = rn(x - hi).
__device__ __forceinline__ void split_bf16(const float* f, bf16x8& hi, bf16x8& lo) {
#pragma unroll
    for (int j = 0; j < 8; ++j) {
        float x = f[j];
        __bf16 h = (__bf16)x;
        hi[j] = h;
        lo[j] = (__bf16)(x - (float)h);
    }
}

// Block: 256 threads = 4 waves. Each block: one (b,h) and a 16-query tile.
// Wave w owns keys [w*256, w*256+256). Swapped QK^T: mfma(A=K, B=Q) so the
// C-layout gives lane -> (query = lane&15, keys = (lane>>4)*4 + r).
__global__ __launch_bounds__(256) void fused_attn_kernel(
    const float* __restrict__ Q, const float* __restrict__ K, const float* __restrict__ V,
    const int* __restrict__ mask, const float* __restrict__ adj, const float* __restrict__ dist,
    float* __restrict__ out_g, float* __restrict__ attn_g)
{
    const int tid  = (int)threadIdx.x;
    const int lane = tid & 63;
    const int wid  = tid >> 6;    // 0..3 : k-range
    const int qi   = lane & 15;   // query (for C/P) or row-in-tile (for A loads)
    const int g    = lane >> 4;   // 0..3

    const int bid = (int)blockIdx.x;
    const int qt  = bid & 63;     // 64 q-tiles of 16
    const int bh  = bid >> 6;     // 0..63
    const int b   = bh >> 4;

    // Per-wave P region: 16 q-rows x 256 keys bf16 (8 KB), XOR-swizzled at
    // 16B-chunk granularity (chunk ^= q&7) for conflict-minimal b128 reads.
    __shared__ __align__(16) unsigned short Plds[4][16 * 256];
    __shared__ __align__(16) float outp[4][16][68];   // +4 pad breaks bank aliasing
    __shared__ float red_m[4][16];
    __shared__ float red_l[4][16];

    const int qglob = qt * 16 + qi;
    const int kw    = wid * 256;

    // ---- Q fragments (B operand): lane reads Q[qglob][c*32 + g*8 + 0..7] / 8
    bf16x8 qh[2], ql[2];
    {
        const float* qp = Q + (bh * NS + qglob) * ND + g * 8;
#pragma unroll
        for (int c = 0; c < 2; ++c) {
            f32x4 f0 = *(const f32x4*)(qp + c * 32);
            f32x4 f1 = *(const f32x4*)(qp + c * 32 + 4);
            float f[8];
#pragma unroll
            for (int j = 0; j < 4; ++j) { f[j] = f0[j] * 0.125f; f[j + 4] = f1[j] * 0.125f; }
            split_bf16(f, qh[c], ql[c]);
        }
    }

    // ---- QK^T with hi/lo error compensation (3 MFMAs per 32-d chunk)
    f32x4 acc[16];
    {
        const f32x4 z = {0.f, 0.f, 0.f, 0.f};
#pragma unroll
        for (int t = 0; t < 16; ++t) acc[t] = z;
    }
#pragma unroll
    for (int t = 0; t < 16; ++t) {
        const float* kp = K + (bh * NS + kw + t * 16 + qi) * ND + g * 8;
#pragma unroll
        for (int c = 0; c < 2; ++c) {
            f32x4 f0 = *(const f32x4*)(kp + c * 32);
            f32x4 f1 = *(const f32x4*)(kp + c * 32 + 4);
            float f[8];
#pragma unroll
            for (int j = 0; j < 4; ++j) { f[j] = f0[j]; f[j + 4] = f1[j]; }
            bf16x8 kh, kl;
            split_bf16(f, kh, kl);
            acc[t] = __builtin_amdgcn_mfma_f32_16x16x32_bf16(kh, qh[c], acc[t], 0, 0, 0);
            acc[t] = __builtin_amdgcn_mfma_f32_16x16x32_bf16(kl, qh[c], acc[t], 0, 0, 0);
            acc[t] = __builtin_amdgcn_mfma_f32_16x16x32_bf16(kh, ql[c], acc[t], 0, 0, 0);
        }
    }

    // ---- elementwise: relu * rescaled + adj, mask -> -1e9
    const float* adjR  = adj  + (b * NS + qglob) * NS;
    const float* distR = dist + (b * NS + qglob) * NS;
    const int*   maskR = mask + b * NS;
    const float  CE = 3.7182817f;  // 1 + e

#pragma unroll
    for (int t = 0; t < 16; ++t) {
        const int k0 = kw + t * 16 + g * 4;
        f32x4 a4 = *(const f32x4*)(adjR + k0);
        f32x4 d4 = *(const f32x4*)(distR + k0);
        int4  m4 = *(const int4*)(maskR + k0);
        int   mm[4] = {m4.x, m4.y, m4.z, m4.w};
#pragma unroll
        for (int r = 0; r < 4; ++r) {
            float s = fmaxf(acc[t][r], 0.f);
            float resc = CE * __builtin_amdgcn_rcpf(1.f + __expf(1.f - d4[r]));
            s = s * resc + a4[r];
            acc[t][r] = (mm[r] == 0) ? -1.0e9f : s;
        }
    }

    // ---- softmax over full 1024-key row (in-lane -> shfl -> LDS cross-wave)
    float m = -3.0e38f;
#pragma unroll
    for (int t = 0; t < 16; ++t)
#pragma unroll
        for (int r = 0; r < 4; ++r) m = fmaxf(m, acc[t][r]);
    m = fmaxf(m, __shfl_xor(m, 16, 64));
    m = fmaxf(m, __shfl_xor(m, 32, 64));
    if (g == 0) red_m[wid][qi] = m;
    __syncthreads();
    const float mf = fmaxf(fmaxf(red_m[0][qi], red_m[1][qi]),
                           fmaxf(red_m[2][qi], red_m[3][qi]));

    float l = 0.f;
#pragma unroll
    for (int t = 0; t < 16; ++t)
#pragma unroll
        for (int r = 0; r < 4; ++r) {
            float e = __expf(acc[t][r] - mf);
            acc[t][r] = e;
            l += e;
        }
    l += __shfl_xor(l, 16, 64);
    l += __shfl_xor(l, 32, 64);
    if (g == 0) red_l[wid][qi] = l;
    __syncthreads();
    const float lf = red_l[0][qi] + red_l[1][qi] + red_l[2][qi] + red_l[3][qi];
    const float inv = __builtin_amdgcn_rcpf(lf);

    // ---- write attn (f32, nontemporal) + pack P to LDS (bf16, swizzled)
    float* attnR = attn_g + (bh * NS + qglob) * NS;
    unsigned short* Pw = &Plds[wid][0];
#pragma unroll
    for (int t = 0; t < 16; ++t) {
        const int kloc = t * 16 + g * 4;
        f32x4 e4;
#pragma unroll
        for (int r = 0; r < 4; ++r) e4[r] = acc[t][r] * inv;
        __builtin_nontemporal_store(e4, (f32x4*)(attnR + kw + kloc));

        unsigned int p01 = ((unsigned int)__builtin_bit_cast(unsigned short, (__bf16)e4[0]))
                         | ((unsigned int)__builtin_bit_cast(unsigned short, (__bf16)e4[1]) << 16);
        unsigned int p23 = ((unsigned int)__builtin_bit_cast(unsigned short, (__bf16)e4[2]))
                         | ((unsigned int)__builtin_bit_cast(unsigned short, (__bf16)e4[3]) << 16);
        const int u = kloc >> 2;          // 8B unit within row
        const int c = u >> 1;             // 16B chunk 0..31
        unsigned long long pk = (unsigned long long)p01 | ((unsigned long long)p23 << 32);
        *(unsigned long long*)((char*)Pw + qi * 512 + ((c ^ (qi & 7)) << 4) + (u & 1) * 8) = pk;
    }
    __syncthreads();

    // ---- PV: A = P (from LDS), B = V (scalar f32 loads -> bf16)
    f32x4 o[4];
    {
        const f32x4 z = {0.f, 0.f, 0.f, 0.f};
#pragma unroll
        for (int dt = 0; dt < 4; ++dt) o[dt] = z;
    }
    const float* vbase = V + (bh * NS + kw) * ND;
#pragma unroll
    for (int j = 0; j < 8; ++j) {                 // 32-key chunks
        const int c = j * 4 + g;
        const u16x8 praw = *(const u16x8*)((const char*)Pw + qi * 512 + ((c ^ (qi & 7)) << 4));
        const bf16x8 pa = __builtin_bit_cast(bf16x8, praw);
        const float* vp0 = vbase + (j * 32 + g * 8) * ND + qi;
#pragma unroll
        for (int dt = 0; dt < 4; ++dt) {          // 16-wide d tiles
            bf16x8 vb;
            const float* vp = vp0 + dt * 16;
#pragma unroll
            for (int r = 0; r < 8; ++r) vb[r] = (__bf16)vp[r * ND];
            o[dt] = __builtin_amdgcn_mfma_f32_16x16x32_bf16(pa, vb, o[dt], 0, 0, 0);
        }
    }

    // ---- cross-wave reduce of out partials (k-split) and store
#pragma unroll
    for (int dt = 0; dt < 4; ++dt)
#pragma unroll
        for (int r = 0; r < 4; ++r)
            outp[wid][g * 4 + r][dt * 16 + qi] = o[dt][r];
    __syncthreads();
    {
        const int qrow = tid >> 4;
        const int d0   = (tid & 15) * 4;
        f32x4 s = *(const f32x4*)(&outp[0][qrow][d0]);
#pragma unroll
        for (int w = 1; w < 4; ++w) s += *(const f32x4*)(&outp[w][qrow][d0]);
        __builtin_nontemporal_store(s, (f32x4*)(out_g + (bh * NS + qt * 16 + qrow) * ND + d0));
    }
}

extern "C" void kernel_launch(void* const* d_in, const int* in_sizes, int n_in,
                              void* d_out, int out_size, void* d_ws, size_t ws_size,
                              hipStream_t stream) {
    const float* Q    = (const float*)d_in[0];
    const float* K    = (const float*)d_in[1];
    const float* V    = (const float*)d_in[2];
    const int*   mask = (const int*)d_in[3];
    const float* adj  = (const float*)d_in[4];
    const float* dist = (const float*)d_in[5];
    float* out  = (float*)d_out;
    float* attn = out + (size_t)NB * NH * NS * ND;   // outputs concatenated: (output, attn)

    dim3 grid(NB * NH * (NS / 16));   // 4096 blocks, bh-major for L2 locality
    fused_attn_kernel<<<grid, 256, 0, stream>>>(Q, K, V, mask, adj, dist, out, attn);
}